// Round 5
// baseline (546.756 us; speedup 1.0000x reference)
//
#include <hip/hip_runtime.h>
#include <stdint.h>

// ---------------------------------------------------------------------------
// StyleBlock: modulated conv3x3 + noise + bias + LeakyReLU. B=16,C=512,HW=64².
// R4 (resubmit; R4 never ran — broker timeout): 3 kernels (k_sw, k_xta, k_conv).
// k_conv = 2-phase prefetch pipeline (double-buffered LDS, one barrier/chunk,
// counted cover for vmcnt), setprio around MFMA, w pitch 64 (R3 inversion),
// demod fused into conv prologue, style-linear fused into k_xta.
// ---------------------------------------------------------------------------

typedef __attribute__((ext_vector_type(8))) short s16x8;
typedef __attribute__((ext_vector_type(4))) float f32x4;

constexpr int CIN = 512, COUT = 512, WD = 512, HW = 4096;
constexpr float C_LIN  = 0.04419417382415922f;    // 1/sqrt(512)
constexpr float C_CONV = 0.014731391274719739f;   // 1/sqrt(4608)
constexpr float CC2    = 1.0f / 4608.0f;

constexpr int WSEG = 2304;                        // 9t x 4s x 64co cells

// ws layout (bytes): A@0 (32KB) | S@32768 (1MB) | wpack@1310720 (4.72MB)
//                    xt@6291456 (69.2MB)
constexpr size_t WS_A = 0, WS_S = 32768;
constexpr size_t WS_WP = 1310720, WS_XT = 6291456;

__device__ __forceinline__ unsigned short f2bf(float f) {
  union { float f; unsigned int u; } v; v.f = f;
  unsigned int u = v.u + 0x7FFFu + ((v.u >> 16) & 1u);
  return (unsigned short)(u >> 16);
}

__device__ __forceinline__ void gload16(const void* g, void* l) {
  __builtin_amdgcn_global_load_lds((const __attribute__((address_space(1))) void*)g,
                                   (__attribute__((address_space(3))) void*)l, 16, 0, 0);
}

// ---------------- k_sw: fused S + wpack (one pass over w_conv)
// wpack seg(ct,ch): cell (t*4+s)*64+co = bf16(w_conv*C_CONV), ci=ch*32+s*8+j
__global__ void k_sw(const float* __restrict__ wc, uint4* __restrict__ wp,
                     float* __restrict__ S) {
  __shared__ float wt[64][289];
  const int ct = blockIdx.x, ch = blockIdx.y, tid = threadIdx.x;
  const int co0 = ct * 64, ci0 = ch * 32;
  for (int i = tid; i < 64 * 288; i += 256) {
    int co = i / 288, r = i - co * 288;
    wt[co][r] = wc[(size_t)(co0 + co) * 4608 + (size_t)ci0 * 9 + r];
  }
  __syncthreads();
  uint4* seg = wp + (size_t)(ct * 16 + ch) * WSEG;
  for (int c = tid; c < 2304; c += 256) {
    int t = c >> 8, rem = c & 255, s = rem >> 6, co = rem & 63;
    union { unsigned short u[8]; uint4 v; } pk;
#pragma unroll
    for (int j = 0; j < 8; ++j) pk.u[j] = f2bf(wt[co][(s*8 + j) * 9 + t] * C_CONV);
    seg[(t * 4 + s) * 64 + co] = pk.v;
  }
  for (int i = tid; i < 2048; i += 256) {
    int co = i >> 5, ci = i & 31;
    float s_ = 0.f;
#pragma unroll
    for (int t = 0; t < 9; ++t) { float v = wt[co][ci * 9 + t]; s_ += v * v; }
    S[(size_t)(co0 + co) * CIN + ci0 + ci] = s_;
  }
}

// ---------------- k_xta: fused style-linear (recomputed per block) + x transform
// grid (64 = ch*4+rowgrp, 16 b), 256 threads.
// xt[b][ch] cell (row*4+s)*66 + 1+col = bf16(x[ci][row][col]*A[ci]), halo 0.
__global__ __launch_bounds__(256) void k_xta(
    const float* __restrict__ x, const float* __restrict__ w,
    const float* __restrict__ wsty, const float* __restrict__ bs,
    float* __restrict__ A, uint4* __restrict__ xt) {
  __shared__ float wl[WD];
  __shared__ float red[256];
  __shared__ float As[32];
  const int p = blockIdx.x, b = blockIdx.y, tid = threadIdx.x;
  const int ch = p >> 2, rowgrp = p & 3, ci0 = ch * 32;
  for (int i = tid; i < WD; i += 256) wl[i] = w[b * WD + i];
  __syncthreads();
  const int ci_l = tid >> 3, part = tid & 7;     // 32 ci x 8 partials
  {
    const float4* row = (const float4*)(wsty + (size_t)(ci0 + ci_l) * WD + part * 64);
    float acc = 0.f;
#pragma unroll
    for (int k = 0; k < 16; ++k) {
      float4 v = row[k];
      acc += v.x * wl[part*64 + 4*k] + v.y * wl[part*64 + 4*k+1]
           + v.z * wl[part*64 + 4*k+2] + v.w * wl[part*64 + 4*k+3];
    }
    red[tid] = acc;
  }
  __syncthreads();
  if (part == 0) {
    float s = 0.f;
#pragma unroll
    for (int q = 0; q < 8; ++q) s += red[ci_l * 8 + q];
    float a = s * C_LIN + bs[ci0 + ci_l];
    As[ci_l] = a;
    if (rowgrp == 0) A[b * CIN + ci0 + ci_l] = a;
  }
  __syncthreads();
  const int lane = tid & 63, wave = tid >> 6;
  const float* xb = x + ((size_t)(b * CIN + ci0) << 12) + lane;
  uint4* dstb = xt + (size_t)((b << 4) + ch) * 16896;
#pragma unroll
  for (int i = 0; i < 4; ++i) {
    const int rw = rowgrp * 16 + wave * 4 + i;
    const float* xr = xb + (rw << 6);
    uint4* dst = dstb + (size_t)(rw * 4) * 66;
#pragma unroll
    for (int s = 0; s < 4; ++s) {
      union { unsigned short u[8]; uint4 v; } pk;
#pragma unroll
      for (int j = 0; j < 8; ++j)
        pk.u[j] = f2bf(xr[(size_t)(s * 8 + j) << 12] * As[s * 8 + j]);
      dst[s * 66 + 1 + lane] = pk.v;
      if (lane < 2) dst[s * 66 + lane * 65] = (uint4){0, 0, 0, 0};
    }
  }
}

// ---------------- k_conv: 64co x 512px tiles, ci-chunk 32, 2-phase pipeline
__global__ __launch_bounds__(512, 2) void k_conv(
    const uint4* __restrict__ xt, const uint4* __restrict__ wp,
    const float* __restrict__ S, const float* __restrict__ A,
    const float* __restrict__ noise, const float* __restrict__ sn_,
    const float* __restrict__ bias, float* __restrict__ out) {

  __shared__ __align__(16) uint4 x_lds[2][2640];   // 10 rows x 4 s x 66 cells
  __shared__ __align__(16) uint4 w_lds[2][WSEG];   // 9 t x 4 s x 64 co
  __shared__ float red[512];
  __shared__ float dm_l[64], bi_l[64];

  const int sp = blockIdx.x, ct = blockIdx.y, b = blockIdx.z;
  const int r0 = sp * 8, co0 = ct * 64;
  const int tid = threadIdx.x, lane = tid & 63, wave = tid >> 6;
  const int l15 = lane & 15, l4 = lane >> 4;

  const int lo = (r0 - 1 > 0) ? r0 - 1 : 0;
  const int hi = (r0 + 8 < 63) ? r0 + 8 : 63;
  const int cells = (hi - lo + 1) * 264;
  const int dst0 = (lo - (r0 - 1)) * 264;      // 0 or 264

  auto stage = [&](int buf, int ch) {
    const uint4* xsrc = xt + ((size_t)(b * 16 + ch) * 64 + lo) * 264;
    for (int i = wave; i * 64 < cells; i += 8)
      if (i * 64 + lane < cells)
        gload16(xsrc + i * 64 + lane, &x_lds[buf][dst0 + i * 64]);
    const uint4* wsrc = wp + (size_t)(ct * 16 + ch) * WSEG;
    for (int i = wave; i < 36; i += 8)
      gload16(wsrc + i * 64 + lane, &w_lds[buf][i * 64]);
  };

  // issue chunk-0 staging first (latency covered by demod prologue below)
  stage(0, 0);

  // halo-row zeros for both buffers (disjoint from staged cells)
  if (sp == 0) for (int i = tid; i < 264; i += 512) {
    x_lds[0][i] = (uint4){0,0,0,0}; x_lds[1][i] = (uint4){0,0,0,0};
  }
  if (sp == 7) for (int i = tid; i < 264; i += 512) {
    x_lds[0][2376+i] = (uint4){0,0,0,0}; x_lds[1][2376+i] = (uint4){0,0,0,0};
  }

  // fused demod: dm[co] = rsqrt(CC2 * sum_ci S[co,ci]*A[b,ci]^2 + eps)
  {
    const int co = tid >> 3, part = tid & 7;   // 64 co x 8 partials
    const float4* srow = (const float4*)(S + (size_t)(co0 + co) * CIN + part * 64);
    const float4* arow = (const float4*)(A + (size_t)b * CIN + part * 64);
    float acc = 0.f;
#pragma unroll
    for (int k = 0; k < 16; ++k) {
      float4 sv = srow[k], av = arow[k];
      acc += sv.x*av.x*av.x + sv.y*av.y*av.y + sv.z*av.z*av.z + sv.w*av.w*av.w;
    }
    red[tid] = acc;
  }
  __syncthreads();
  if (tid < 64) {
    float s_ = 0.f;
#pragma unroll
    for (int q = 0; q < 8; ++q) s_ += red[tid * 8 + q];
    dm_l[tid] = rsqrtf(CC2 * s_ + 1e-8f);
    bi_l[tid] = bias[co0 + tid];
  }

  f32x4 acc[4][4];
#pragma unroll
  for (int m = 0; m < 4; ++m)
#pragma unroll
    for (int f = 0; f < 4; ++f) acc[m][f] = (f32x4){0.f, 0.f, 0.f, 0.f};

  __syncthreads();   // chunk-0 staging + dm_l/bi_l complete

  for (int ch = 0; ch < 16; ++ch) {
    const int buf = ch & 1;
    if (ch < 15) stage(buf ^ 1, ch + 1);     // issue next-chunk loads EARLY

#pragma unroll
    for (int t = 0; t < 9; ++t) {
      const int dh = t / 3, dw = t - dh * 3;
      s16x8 afr[4], bfr[4];
#pragma unroll
      for (int m = 0; m < 4; ++m)
        afr[m] = *(const s16x8*)&w_lds[buf][(t * 4 + l4) * 64 + m * 16 + l15];
#pragma unroll
      for (int f = 0; f < 4; ++f)
        bfr[f] = *(const s16x8*)&x_lds[buf][((wave + dh) * 4 + l4) * 66 + f * 16 + l15 + dw];
      __builtin_amdgcn_s_setprio(1);
#pragma unroll
      for (int m = 0; m < 4; ++m)
#pragma unroll
        for (int f = 0; f < 4; ++f)
          acc[m][f] = __builtin_amdgcn_mfma_f32_16x16x32_bf16(afr[m], bfr[f], acc[m][f], 0, 0, 0);
      __builtin_amdgcn_s_setprio(0);
    }
    __syncthreads();   // vmcnt(0) here waits loads issued before the 9-tap compute
  }

  const float sn = sn_[0];
  const int row = r0 + wave;
  float nz[4];
#pragma unroll
  for (int f = 0; f < 4; ++f) nz[f] = sn * noise[b * HW + row * 64 + f * 16 + l15];
#pragma unroll
  for (int m = 0; m < 4; ++m) {
#pragma unroll
    for (int reg = 0; reg < 4; ++reg) {
      const int co_l = m * 16 + l4 * 4 + reg;
      const float d = dm_l[co_l], bv = bi_l[co_l];
      float* op = out + ((size_t)(b * COUT + co0 + co_l)) * HW + row * 64;
#pragma unroll
      for (int f = 0; f < 4; ++f) {
        float v = d * acc[m][f][reg] + nz[f] + bv;
        op[f * 16 + l15] = (v >= 0.f) ? v : 0.2f * v;
      }
    }
  }
}

// ---------------------------------------------------------------------------
extern "C" void kernel_launch(void* const* d_in, const int* in_sizes, int n_in,
                              void* d_out, int out_size, void* d_ws, size_t ws_size,
                              hipStream_t stream) {
  (void)in_sizes; (void)n_in; (void)out_size; (void)ws_size;
  const float* x           = (const float*)d_in[0];
  const float* w           = (const float*)d_in[1];
  const float* noise       = (const float*)d_in[2];
  const float* w_style     = (const float*)d_in[3];
  const float* b_style     = (const float*)d_in[4];
  const float* w_conv      = (const float*)d_in[5];
  const float* scale_noise = (const float*)d_in[6];
  const float* bias        = (const float*)d_in[7];
  float* out = (float*)d_out;

  char* ws = (char*)d_ws;
  float* A     = (float*)(ws + WS_A);
  float* S     = (float*)(ws + WS_S);
  uint4* wpack = (uint4*)(ws + WS_WP);
  uint4* xt    = (uint4*)(ws + WS_XT);

  k_sw<<<dim3(8, 16), 256, 0, stream>>>(w_conv, wpack, S);
  k_xta<<<dim3(64, 16), 256, 0, stream>>>(x, w, w_style, b_style, A, xt);
  k_conv<<<dim3(8, 8, 16), 512, 0, stream>>>(xt, wpack, S, A, noise, scale_noise, bias, out);
}

// Round 6
// 544.932 us; speedup vs baseline: 1.0033x; 1.0033x over previous
//
#include <hip/hip_runtime.h>
#include <stdint.h>

// ---------------------------------------------------------------------------
// StyleBlock: modulated conv3x3 + noise + bias + LeakyReLU. B=16,C=512,HW=64².
// R6: R2 skeleton (single buffer, 2 blocks/CU) + DPP-derived dw fragments
//     (bfr reads 36->15/wave/chunk) + pitch-64 x layout w/ edge plane
//     (conflict-free reads). dm/bi folded into red to fit 80.5KB LDS.
// ---------------------------------------------------------------------------

typedef __attribute__((ext_vector_type(8))) short s16x8;
typedef __attribute__((ext_vector_type(4))) float f32x4;

constexpr int CIN = 512, COUT = 512, WD = 512, HW = 4096;
constexpr float C_LIN  = 0.04419417382415922f;    // 1/sqrt(512)
constexpr float C_CONV = 0.014731391274719739f;   // 1/sqrt(4608)
constexpr float CC2    = 1.0f / 4608.0f;

constexpr int WSEG = 2304;                        // 9t x 4s x 64co cells
constexpr int XSEG = 16640;                       // 16384 main + 256 edge cells

// ws layout (bytes): A@0 (32KB) | S@32768 (1MB) | wpack@1310720 (4.72MB)
//                    xt@6291456 (68.2MB)
constexpr size_t WS_A = 0, WS_S = 32768;
constexpr size_t WS_WP = 1310720, WS_XT = 6291456;

__device__ __forceinline__ unsigned short f2bf(float f) {
  union { float f; unsigned int u; } v; v.f = f;
  unsigned int u = v.u + 0x7FFFu + ((v.u >> 16) & 1u);
  return (unsigned short)(u >> 16);
}

__device__ __forceinline__ void gload16(const void* g, void* l) {
  __builtin_amdgcn_global_load_lds((const __attribute__((address_space(1))) void*)g,
                                   (__attribute__((address_space(3))) void*)l, 16, 0, 0);
}

union I4H8 { int4 i; s16x8 h; uint4 u; };

// dmix: per-dword (dpp(a, CA) | dpp(b, CB)), bound_ctrl:0 (invalid lanes -> 0)
template <int CA, int CB>
__device__ __forceinline__ int4 dmix(int4 a, int4 b) {
  int4 r;
  r.x = __builtin_amdgcn_mov_dpp(a.x, CA, 0xF, 0xF, true) |
        __builtin_amdgcn_mov_dpp(b.x, CB, 0xF, 0xF, true);
  r.y = __builtin_amdgcn_mov_dpp(a.y, CA, 0xF, 0xF, true) |
        __builtin_amdgcn_mov_dpp(b.y, CB, 0xF, 0xF, true);
  r.z = __builtin_amdgcn_mov_dpp(a.z, CA, 0xF, 0xF, true) |
        __builtin_amdgcn_mov_dpp(b.z, CB, 0xF, 0xF, true);
  r.w = __builtin_amdgcn_mov_dpp(a.w, CA, 0xF, 0xF, true) |
        __builtin_amdgcn_mov_dpp(b.w, CB, 0xF, 0xF, true);
  return r;
}

// ---------------- k_sw: fused S + wpack (one pass over w_conv)
__global__ void k_sw(const float* __restrict__ wc, uint4* __restrict__ wp,
                     float* __restrict__ S) {
  __shared__ float wt[64][289];
  const int ct = blockIdx.x, ch = blockIdx.y, tid = threadIdx.x;
  const int co0 = ct * 64, ci0 = ch * 32;
  for (int i = tid; i < 64 * 288; i += 256) {
    int co = i / 288, r = i - co * 288;
    wt[co][r] = wc[(size_t)(co0 + co) * 4608 + (size_t)ci0 * 9 + r];
  }
  __syncthreads();
  uint4* seg = wp + (size_t)(ct * 16 + ch) * WSEG;
  for (int c = tid; c < 2304; c += 256) {
    int t = c >> 8, rem = c & 255, s = rem >> 6, co = rem & 63;
    union { unsigned short u[8]; uint4 v; } pk;
#pragma unroll
    for (int j = 0; j < 8; ++j) pk.u[j] = f2bf(wt[co][(s*8 + j) * 9 + t] * C_CONV);
    seg[(t * 4 + s) * 64 + co] = pk.v;
  }
  for (int i = tid; i < 2048; i += 256) {
    int co = i >> 5, ci = i & 31;
    float s_ = 0.f;
#pragma unroll
    for (int t = 0; t < 9; ++t) { float v = wt[co][ci * 9 + t]; s_ += v * v; }
    S[(size_t)(co0 + co) * CIN + ci0 + ci] = s_;
  }
}

// ---------------- k_xta: fused style-linear + x transform (layout v2)
// xt[b][ch]: main cell (row*4+s)*64 + c = pixel c-1 (c=0 -> 0); edge cell
// 16384 + row*4+s = pixel 63. Content bf16(x*A).
__global__ __launch_bounds__(256) void k_xta(
    const float* __restrict__ x, const float* __restrict__ w,
    const float* __restrict__ wsty, const float* __restrict__ bs,
    float* __restrict__ A, uint4* __restrict__ xt) {
  __shared__ float wl[WD];
  __shared__ float red[256];
  __shared__ float As[32];
  const int p = blockIdx.x, b = blockIdx.y, tid = threadIdx.x;
  const int ch = p >> 2, rowgrp = p & 3, ci0 = ch * 32;
  for (int i = tid; i < WD; i += 256) wl[i] = w[b * WD + i];
  __syncthreads();
  const int ci_l = tid >> 3, part = tid & 7;     // 32 ci x 8 partials
  {
    const float4* row = (const float4*)(wsty + (size_t)(ci0 + ci_l) * WD + part * 64);
    float acc = 0.f;
#pragma unroll
    for (int k = 0; k < 16; ++k) {
      float4 v = row[k];
      acc += v.x * wl[part*64 + 4*k] + v.y * wl[part*64 + 4*k+1]
           + v.z * wl[part*64 + 4*k+2] + v.w * wl[part*64 + 4*k+3];
    }
    red[tid] = acc;
  }
  __syncthreads();
  if (part == 0) {
    float s = 0.f;
#pragma unroll
    for (int q = 0; q < 8; ++q) s += red[ci_l * 8 + q];
    float a = s * C_LIN + bs[ci0 + ci_l];
    As[ci_l] = a;
    if (rowgrp == 0) A[b * CIN + ci0 + ci_l] = a;
  }
  __syncthreads();
  const int lane = tid & 63, wave = tid >> 6;
  const int px = (lane == 0) ? 63 : lane - 1;    // lane0 computes the edge cell
  const float* xb = x + ((size_t)(b * CIN + ci0) << 12) + px;
  uint4* seg = xt + (size_t)((b << 4) + ch) * XSEG;
#pragma unroll
  for (int i = 0; i < 4; ++i) {
    const int row = rowgrp * 16 + wave * 4 + i;
    const float* xr = xb + (row << 6);
#pragma unroll
    for (int s = 0; s < 4; ++s) {
      union { unsigned short u[8]; uint4 v; } pk;
#pragma unroll
      for (int j = 0; j < 8; ++j)
        pk.u[j] = f2bf(xr[(size_t)(s * 8 + j) << 12] * As[s * 8 + j]);
      if (lane == 0) {
        seg[16384 + row * 4 + s] = pk.v;              // pixel 63 (edge plane)
        seg[(row * 4 + s) * 64] = (uint4){0, 0, 0, 0}; // left halo (pixel -1)
      } else {
        seg[(row * 4 + s) * 64 + lane] = pk.v;        // pixels 0..62
      }
    }
  }
}

// ---------------- k_conv: 64co x 512px tiles, ci-chunk 32, single buffer,
// 2 blocks/CU, DPP-derived dw fragments.
__global__ __launch_bounds__(512, 4) void k_conv(
    const uint4* __restrict__ xt, const uint4* __restrict__ wp,
    const float* __restrict__ S, const float* __restrict__ A,
    const float* __restrict__ noise, const float* __restrict__ sn_,
    const float* __restrict__ bias, float* __restrict__ out) {

  __shared__ __align__(16) uint4 xm_lds[2560];   // 10 rows x 4 s x 64 cells
  __shared__ __align__(16) uint4 xe_lds[40];     // 10 rows x 4 s edge cells
  __shared__ __align__(16) uint4 w_lds[WSEG];    // 9 t x 4 s x 64 co
  __shared__ float red[512];                     // demod scratch; then dm[0:64], bi[64:128]

  const int sp = blockIdx.x, ct = blockIdx.y, b = blockIdx.z;
  const int r0 = sp * 8, co0 = ct * 64;
  const int tid = threadIdx.x, lane = tid & 63, wave = tid >> 6;
  const int l15 = lane & 15, l4 = lane >> 4;
  const bool l15z = (l15 == 0);

  const int lo = (r0 - 1 > 0) ? r0 - 1 : 0;
  const int hi = (r0 + 8 < 63) ? r0 + 8 : 63;
  const int nrows = hi - lo + 1;
  const int dst0 = (lo - (r0 - 1)) * 256;        // 0 or 256
  const int edst0 = (lo - (r0 - 1)) * 4;

  auto stage = [&](int ch) {
    const uint4* seg = xt + (size_t)(b * 16 + ch) * XSEG;
    const uint4* xsrc = seg + (size_t)lo * 256;
    const int nI = nrows * 4;                    // 64-cell groups
    for (int i = wave; i < nI; i += 8)
      gload16(xsrc + i * 64 + lane, &xm_lds[dst0 + i * 64]);
    const uint4* esrc = seg + 16384 + lo * 4;
    if (wave == 0 && lane < nrows * 4)
      gload16(esrc + lane, &xe_lds[edst0 + lane]);
    const uint4* wsrc = wp + (size_t)(ct * 16 + ch) * WSEG;
    for (int i = wave; i < 36; i += 8)
      gload16(wsrc + i * 64 + lane, &w_lds[i * 64]);
  };

  stage(0);

  // vertical-halo zero rows (outside staged range; persist across chunks)
  if (sp == 0) {
    for (int i = tid; i < 256; i += 512) xm_lds[i] = (uint4){0, 0, 0, 0};
    if (tid < 4) xe_lds[tid] = (uint4){0, 0, 0, 0};
  }
  if (sp == 7) {
    for (int i = tid; i < 256; i += 512) xm_lds[2304 + i] = (uint4){0, 0, 0, 0};
    if (tid < 4) xe_lds[36 + tid] = (uint4){0, 0, 0, 0};
  }

  // fused demod partials: sum_ci S[co,ci]*A[b,ci]^2
  {
    const int co = tid >> 3, part = tid & 7;     // 64 co x 8 partials
    const float4* srow = (const float4*)(S + (size_t)(co0 + co) * CIN + part * 64);
    const float4* arow = (const float4*)(A + (size_t)b * CIN + part * 64);
    float acc = 0.f;
#pragma unroll
    for (int k = 0; k < 16; ++k) {
      float4 sv = srow[k], av = arow[k];
      acc += sv.x*av.x*av.x + sv.y*av.y*av.y + sv.z*av.z*av.z + sv.w*av.w*av.w;
    }
    red[tid] = acc;
  }
  __syncthreads();               // red ready; also drains chunk-0 staging
  float dmv = 0.f;
  if (tid < 64) {
#pragma unroll
    for (int q = 0; q < 8; ++q) dmv += red[tid * 8 + q];
  }
  __syncthreads();               // all reads of red done before overwrite
  if (tid < 64) {
    red[tid] = rsqrtf(CC2 * dmv + 1e-8f);
    red[64 + tid] = bias[co0 + tid];
  }

  f32x4 acc[4][4];
#pragma unroll
  for (int m = 0; m < 4; ++m)
#pragma unroll
    for (int f = 0; f < 4; ++f) acc[m][f] = (f32x4){0.f, 0.f, 0.f, 0.f};
  __syncthreads();

  for (int ch = 0; ch < 16; ++ch) {
#pragma unroll
    for (int dh = 0; dh < 3; ++dh) {
      const int rb = (wave + dh) * 4 + l4;
      I4H8 d0[4], eF;
#pragma unroll
      for (int f = 0; f < 4; ++f) d0[f].u = xm_lds[rb * 64 + f * 16 + l15];
      {
        I4H8 e; e.u = xe_lds[rb];
        eF.i.x = l15z ? e.i.x : 0;
        eF.i.y = l15z ? e.i.y : 0;
        eF.i.z = l15z ? e.i.z : 0;
        eF.i.w = l15z ? e.i.w : 0;   // lane0 = pixel63, lane1 = 0 (right halo)
      }
#pragma unroll
      for (int dw = 0; dw < 3; ++dw) {
        I4H8 bf[4];
        if (dw == 0) {
#pragma unroll
          for (int f = 0; f < 4; ++f) bf[f] = d0[f];
        } else if (dw == 1) {
#pragma unroll
          for (int f = 0; f < 4; ++f)
            bf[f].i = dmix<0x101, 0x11F>(d0[f].i, (f < 3) ? d0[f + 1].i : eF.i);
        } else {
#pragma unroll
          for (int f = 0; f < 4; ++f)
            bf[f].i = dmix<0x102, 0x11E>(d0[f].i, (f < 3) ? d0[f + 1].i : eF.i);
        }
        const int t = dh * 3 + dw;
#pragma unroll
        for (int m = 0; m < 4; ++m) {
          s16x8 a = *(const s16x8*)&w_lds[(t * 4 + l4) * 64 + m * 16 + l15];
#pragma unroll
          for (int f = 0; f < 4; ++f)
            acc[m][f] = __builtin_amdgcn_mfma_f32_16x16x32_bf16(a, bf[f].h, acc[m][f], 0, 0, 0);
        }
      }
    }
    __syncthreads();             // all LDS reads of this chunk done
    if (ch < 15) stage(ch + 1);
    __syncthreads();             // staged writes visible (vmcnt drained)
  }

  const float sn = sn_[0];
  const int row = r0 + wave;
  float nz[4];
#pragma unroll
  for (int f = 0; f < 4; ++f) nz[f] = sn * noise[b * HW + row * 64 + f * 16 + l15];
#pragma unroll
  for (int m = 0; m < 4; ++m) {
#pragma unroll
    for (int reg = 0; reg < 4; ++reg) {
      const int co_l = m * 16 + l4 * 4 + reg;
      const float d = red[co_l], bv = red[64 + co_l];
      float* op = out + ((size_t)(b * COUT + co0 + co_l)) * HW + row * 64;
#pragma unroll
      for (int f = 0; f < 4; ++f) {
        float v = d * acc[m][f][reg] + nz[f] + bv;
        op[f * 16 + l15] = (v >= 0.f) ? v : 0.2f * v;
      }
    }
  }
}

// ---------------------------------------------------------------------------
extern "C" void kernel_launch(void* const* d_in, const int* in_sizes, int n_in,
                              void* d_out, int out_size, void* d_ws, size_t ws_size,
                              hipStream_t stream) {
  (void)in_sizes; (void)n_in; (void)out_size; (void)ws_size;
  const float* x           = (const float*)d_in[0];
  const float* w           = (const float*)d_in[1];
  const float* noise       = (const float*)d_in[2];
  const float* w_style     = (const float*)d_in[3];
  const float* b_style     = (const float*)d_in[4];
  const float* w_conv      = (const float*)d_in[5];
  const float* scale_noise = (const float*)d_in[6];
  const float* bias        = (const float*)d_in[7];
  float* out = (float*)d_out;

  char* ws = (char*)d_ws;
  float* A     = (float*)(ws + WS_A);
  float* S     = (float*)(ws + WS_S);
  uint4* wpack = (uint4*)(ws + WS_WP);
  uint4* xt    = (uint4*)(ws + WS_XT);

  k_sw<<<dim3(8, 16), 256, 0, stream>>>(w_conv, wpack, S);
  k_xta<<<dim3(64, 16), 256, 0, stream>>>(x, w, w_style, b_style, A, xt);
  k_conv<<<dim3(8, 8, 16), 512, 0, stream>>>(xt, wpack, S, A, noise, scale_noise, bias, out);
}